// Round 4
// baseline (1049.693 us; speedup 1.0000x reference)
//
#include <hip/hip_runtime.h>
#include <cstdint>
#include <cstddef>

#define D_MODEL 768
#define D_SAE   24576
#define KSEL    32
#define NBATCH  4096

typedef _Float16 f16x8 __attribute__((ext_vector_type(8)));
typedef _Float16 f16x4 __attribute__((ext_vector_type(4)));
typedef float    f32x4 __attribute__((ext_vector_type(4)));

// f16 element counts of the split matrices (stored in the z_sparse region as scratch)
#define W_ELEMS  ((size_t)D_MODEL * D_SAE)   // 18,874,368
#define X_ELEMS  ((size_t)NBATCH * D_MODEL)  // 3,145,728

#define TCAND 2.0f      // candidate threshold: ~560 of 24576 N(0,1) exceed it
#define CAP_G 1536      // per-row global candidate capacity

// ---------------------------------------------------------------------------
// split_x: X[4096][768] f32 -> Xh,Xl' blocked f16  (xl' = (x - xh)*2^11)
// ---------------------------------------------------------------------------
__global__ void split_x(const float* __restrict__ X,
                        _Float16* __restrict__ Xh, _Float16* __restrict__ Xl)
{
  const int tile = blockIdx.x;
  const int mb = tile / 12, kb = tile % 12;
  const int t = threadIdx.x;
#pragma unroll
  for (int r = 0; r < 8; ++r) {
    const int flat4 = r * 256 + t;          // 0..2047
    const int m  = flat4 >> 4;              // 0..127
    const int k4 = (flat4 & 15) << 2;       // 0,4,...,60
    const float4 v = *reinterpret_cast<const float4*>(
        &X[(size_t)(mb * 128 + m) * D_MODEL + kb * 64 + k4]);
    const float xx[4] = {v.x, v.y, v.z, v.w};
    f16x4 h, l;
#pragma unroll
    for (int c = 0; c < 4; ++c) {
      const _Float16 hh = (_Float16)xx[c];
      h[c] = hh;
      l[c] = (_Float16)((xx[c] - (float)hh) * 2048.0f);
    }
    const size_t base = ((size_t)(mb * 12 + kb)) * 8192 +
                        m * 64 + (((k4 >> 3) ^ (m & 7)) << 3) + (k4 & 7);
    *reinterpret_cast<f16x4*>(&Xh[base]) = h;
    *reinterpret_cast<f16x4*>(&Xl[base]) = l;
  }
}

// ---------------------------------------------------------------------------
// split_w: W[768][24576] f32 -> Wh,Wl' blocked-TRANSPOSED f16 tiles [n][k]
// ---------------------------------------------------------------------------
__global__ void split_w(const float* __restrict__ W,
                        _Float16* __restrict__ Wh, _Float16* __restrict__ Wl)
{
  __shared__ float Ws[64][129];
  const int tile = blockIdx.x;
  const int nb = tile / 12, kb = tile % 12;
  const int t = threadIdx.x;
#pragma unroll
  for (int r = 0; r < 8; ++r) {
    const int flat4 = r * 256 + t;
    const int k  = flat4 >> 5;              // 0..63
    const int n4 = (flat4 & 31) << 2;       // 0..124
    const float4 v = *reinterpret_cast<const float4*>(
        &W[(size_t)(kb * 64 + k) * D_SAE + nb * 128 + n4]);
    Ws[k][n4 + 0] = v.x; Ws[k][n4 + 1] = v.y; Ws[k][n4 + 2] = v.z; Ws[k][n4 + 3] = v.w;
  }
  __syncthreads();
#pragma unroll
  for (int r = 0; r < 4; ++r) {
    const int u = r * 256 + t;              // 0..1023
    const int n = u >> 3;                   // 0..127
    const int c = u & 7;                    // k-octet
    f16x8 h, l;
#pragma unroll
    for (int i = 0; i < 8; ++i) {
      const float w = Ws[c * 8 + i][n];
      const _Float16 hh = (_Float16)w;
      h[i] = hh;
      l[i] = (_Float16)((w - (float)hh) * 2048.0f);
    }
    const size_t base = ((size_t)(nb * 12 + kb)) * 8192 + n * 64 + ((c ^ (n & 7)) << 3);
    *reinterpret_cast<f16x8*>(&Wh[base]) = h;
    *reinterpret_cast<f16x8*>(&Wl[base]) = l;
  }
}

// ---------------------------------------------------------------------------
__global__ void zero_cnt(int* cnt) { cnt[blockIdx.x * 256 + threadIdx.x] = 0; }

// ---------------------------------------------------------------------------
// gemm_split (FUSED): one K-loop stages Ah/Al/Bh/Bl per K-step and issues all
// three products:  acc_hi += ah@bh ; acc_lo += ah@bl + al@bh.
// Zp = acc_hi + acc_lo*2^-11 + be.  96 MFMA per barrier-pair.
// ---------------------------------------------------------------------------
__device__ __forceinline__ void gll16(void* lds, const void* g) {
  __builtin_amdgcn_global_load_lds(
      (const __attribute__((address_space(1))) unsigned int*)g,
      (__attribute__((address_space(3))) unsigned int*)lds, 16, 0, 0);
}

template <int APPEND>
__global__ __launch_bounds__(256, 2) void gemm_split(
    const _Float16* __restrict__ Xh, const _Float16* __restrict__ Xl,
    const _Float16* __restrict__ Wh, const _Float16* __restrict__ Wl,
    const float* __restrict__ be, float* __restrict__ Zp,
    uint2* __restrict__ cand, int* __restrict__ cnt)
{
  __shared__ char lds[65536];
  char* Ah = lds;
  char* Al = lds + 16384;
  char* Bh = lds + 32768;
  char* Bl = lds + 49152;

  const int bid = blockIdx.x;
  const int wg  = (bid & 7) * 768 + (bid >> 3);   // XCD-contiguous chunks
  const int mb  = wg & 31;
  const int nb  = wg >> 5;

  const int t = threadIdx.x, lane = t & 63, w = t >> 6;
  const int wr = w >> 1, wc = w & 1;
  const int l15 = lane & 15, lq = lane >> 4;
  const int c0 = lq ^ (lane & 7);
  const int offA0 = (wr * 64 + l15) * 128 + c0 * 16;
  const int offB0 = (wc * 64 + l15) * 128 + c0 * 16;

  f32x4 acc_hi[4][4] = {};
  f32x4 acc_lo[4][4] = {};

  const char* gAh = (const char*)Xh + (size_t)mb * 12 * 16384 + t * 16;
  const char* gAl = (const char*)Xl + (size_t)mb * 12 * 16384 + t * 16;
  const char* gBh = (const char*)Wh + (size_t)nb * 12 * 16384 + t * 16;
  const char* gBl = (const char*)Wl + (size_t)nb * 12 * 16384 + t * 16;

  const int dstoff = (t & 192) * 16;   // wave-uniform LDS base (+ lane*16 implicit)

  for (int ks = 0; ks < 12; ++ks) {
    __syncthreads();                   // prior readers done
    const int go = ks * 16384;
#pragma unroll
    for (int r = 0; r < 4; ++r) {
      gll16(Ah + dstoff + r * 4096, gAh + go + r * 4096);
      gll16(Al + dstoff + r * 4096, gAl + go + r * 4096);
      gll16(Bh + dstoff + r * 4096, gBh + go + r * 4096);
      gll16(Bl + dstoff + r * 4096, gBl + go + r * 4096);
    }
    asm volatile("s_waitcnt vmcnt(0)" ::: "memory");
    __syncthreads();
#pragma unroll
    for (int kk = 0; kk < 2; ++kk) {
      f16x8 ah[4], al[4], bh[4], bl[4];
#pragma unroll
      for (int i = 0; i < 4; ++i) {
        const int o = (offA0 + i * 2048) ^ (kk * 64);
        ah[i] = *reinterpret_cast<const f16x8*>(Ah + o);
        al[i] = *reinterpret_cast<const f16x8*>(Al + o);
      }
#pragma unroll
      for (int j = 0; j < 4; ++j) {
        const int o = (offB0 + j * 2048) ^ (kk * 64);
        bh[j] = *reinterpret_cast<const f16x8*>(Bh + o);
        bl[j] = *reinterpret_cast<const f16x8*>(Bl + o);
      }
#pragma unroll
      for (int i = 0; i < 4; ++i)
#pragma unroll
        for (int j = 0; j < 4; ++j) {
          acc_hi[i][j] = __builtin_amdgcn_mfma_f32_16x16x32_f16(ah[i], bh[j], acc_hi[i][j], 0, 0, 0);
          acc_lo[i][j] = __builtin_amdgcn_mfma_f32_16x16x32_f16(ah[i], bl[j], acc_lo[i][j], 0, 0, 0);
          acc_lo[i][j] = __builtin_amdgcn_mfma_f32_16x16x32_f16(al[i], bh[j], acc_lo[i][j], 0, 0, 0);
        }
    }
  }

  // epilogue: combine, + b_enc, store, optional candidate append
  const int m0  = mb * 128 + wr * 64 + (lq << 2);
  const int n0g = nb * 128 + wc * 64 + l15;
#pragma unroll
  for (int j = 0; j < 4; ++j) {
    const int col = n0g + j * 16;
    const float bej = be[col];
#pragma unroll
    for (int i = 0; i < 4; ++i) {
      float* dst = &Zp[(size_t)(m0 + i * 16) * D_SAE + col];
      const f32x4 o4 = acc_hi[i][j] + acc_lo[i][j] * (1.0f / 2048.0f);
#pragma unroll
      for (int rg = 0; rg < 4; ++rg) {
        const float o = o4[rg] + bej;
        dst[(size_t)rg * D_SAE] = o;
        if (APPEND && o > TCAND) {
          const int row = m0 + i * 16 + rg;
          const int slot = atomicAdd(&cnt[row], 1);
          if (slot < CAP_G)
            cand[(size_t)row * CAP_G + slot] = make_uint2(__float_as_uint(o), (uint32_t)col);
        }
      }
    }
  }
}

// ---------------------------------------------------------------------------
// wave ballot-compacted LDS append
// ---------------------------------------------------------------------------
__device__ __forceinline__ void wave_append(uint32_t* dv, uint32_t* di, int* counter,
                                            bool pred, uint32_t v, uint32_t idx, int cap)
{
  const unsigned long long m = __ballot(pred ? 1 : 0);
  if (m == 0ull) return;
  const int lane = threadIdx.x & 63;
  const int leader = __ffsll(m) - 1;
  int wbase = 0;
  if (lane == leader) wbase = atomicAdd(counter, __popcll(m));
  wbase = __shfl(wbase, leader);
  if (pred) {
    const int p = wbase + (int)__popcll(m & ((1ull << lane) - 1ull));
    if (p < cap) { dv[p] = v; di[p] = idx; }
  }
}

// ---------------------------------------------------------------------------
// select_scatter_decode: per row, exact top-32 from the candidate list
// (fallback: full Zpre rescan if count outside [KSEL, CAP_G]), then zero-fill
// z_sparse row + scatter 32 + fused sparse decode.  One kernel, no selbuf.
// ---------------------------------------------------------------------------
__global__ __launch_bounds__(256, 4) void select_scatter_decode(
    const float* __restrict__ Zpre, const uint2* __restrict__ cand,
    const int* __restrict__ cnt, const float* __restrict__ Wd,
    const float* __restrict__ bd, float* __restrict__ Zs, float* __restrict__ Xr)
{
  __shared__ uint32_t cvA[CAP_G], ciA[CAP_G], cvB[CAP_G], ciB[CAP_G];
  __shared__ uint32_t hist[4][256];
  __shared__ uint32_t sel_v[KSEL], sel_i[KSEL];
  __shared__ int nc_sh, sel_sh, new_sh, bin_sh, cg_sh;

  const int row  = blockIdx.x;
  const int t    = threadIdx.x;
  const int wave = t >> 6;
  const int n_glob = cnt[row];
  int n_cur;

  if (n_glob >= KSEL && n_glob <= CAP_G) {
    // fast path: candidates pre-collected by the GEMM epilogue
    for (int j = t; j < n_glob; j += 256) {
      const uint2 p = cand[(size_t)row * CAP_G + j];
      cvA[j] = p.x; ciA[j] = p.y;
    }
    n_cur = n_glob;
    __syncthreads();
  } else {
    // rare fallback: adaptive-threshold full-row scan
    const float* zrow = Zpre + (size_t)row * D_SAE;
    if (t == 0) nc_sh = 0;
    __syncthreads();
    float T0 = (n_glob > CAP_G) ? 4.0f : 0.5f;
    for (int tries = 0; ; ++tries) {
      for (int j4 = t; j4 < D_SAE / 4; j4 += 256) {
        const float4 z4 = *reinterpret_cast<const float4*>(zrow + 4 * j4);
        const float zz[4] = {z4.x, z4.y, z4.z, z4.w};
#pragma unroll
        for (int c = 0; c < 4; ++c) {
          const float v = zz[c] > 0.0f ? zz[c] : 0.0f;
          wave_append(cvA, ciA, &nc_sh, v > T0, __float_as_uint(v),
                      (uint32_t)(4 * j4 + c), CAP_G);
        }
      }
      __syncthreads();
      n_cur = nc_sh;
      if ((n_cur >= KSEL && n_cur <= CAP_G) || tries >= 9) break;
      __syncthreads();
      if (t == 0) nc_sh = 0;
      T0 = (n_cur < KSEL) ? ((tries >= 6) ? 0.0f : T0 * 0.25f) : T0 * 2.0f;
      __syncthreads();
    }
    if (n_cur > CAP_G) n_cur = CAP_G;
  }

  // ---- radix select top-32 (all values >= 0 => bit pattern monotone) ----
  if (t == 0) sel_sh = 0;
  __syncthreads();
  uint32_t* cv = cvA; uint32_t* ci = ciA;
  uint32_t* nv = cvB; uint32_t* ni = ciB;
  int need = KSEL;

  for (int L = 3; L >= 0; --L) {
    if (need <= 0 || n_cur <= 0) break;
    hist[0][t] = 0; hist[1][t] = 0; hist[2][t] = 0; hist[3][t] = 0;
    __syncthreads();
    for (int j = t; j < n_cur; j += 256)
      atomicAdd(&hist[wave][(cv[j] >> (L * 8)) & 255u], 1u);
    __syncthreads();
    if (t == 0) {
      int cum = 0, b = 255;
      for (; b >= 0; --b) {
        const int h = (int)(hist[0][b] + hist[1][b] + hist[2][b] + hist[3][b]);
        if (cum + h >= need) break;
        cum += h;
      }
      bin_sh = b; cg_sh = cum; new_sh = 0;
    }
    __syncthreads();
    const int B = bin_sh;
    const int rounds = (n_cur + 255) / 256;
    for (int rd = 0; rd < rounds; ++rd) {
      const int j = rd * 256 + t;
      const bool valid = j < n_cur;
      const uint32_t v  = valid ? cv[j] : 0u;
      const uint32_t ix = valid ? ci[j] : 0u;
      const int by = valid ? (int)((v >> (L * 8)) & 255u) : -1;
      wave_append(sel_v, sel_i, &sel_sh, valid && by > B, v, ix, KSEL);
      wave_append(nv, ni, &new_sh, valid && by == B, v, ix, CAP_G);
    }
    __syncthreads();
    need -= cg_sh;
    n_cur = new_sh < CAP_G ? new_sh : CAP_G;
    uint32_t* tv = cv; cv = nv; nv = tv;
    uint32_t* ti = ci; ci = ni; ni = ti;
  }

  // ---- exact-tie fill (lowest indices first) + val==0 padding ----
  if (t == 0) {
    int s = sel_sh;
    const int take = (need < n_cur ? need : n_cur);
    uint32_t last = 0u; bool first = true;
    for (int r = 0; r < take; ++r) {
      uint32_t best = 0xFFFFFFFFu, bv = 0u;
      for (int j = 0; j < n_cur; ++j) {
        const uint32_t ix = ci[j];
        if ((first || ix > last) && ix < best) { best = ix; bv = cv[j]; }
      }
      sel_v[s] = bv; sel_i[s] = best; ++s; last = best; first = false;
    }
    for (; s < KSEL; ++s) { sel_v[s] = 0u; sel_i[s] = 0u; }
  }
  __syncthreads();

  // ---- zero-fill z_sparse row + scatter 32 ----
  float* zsrow = Zs + (size_t)row * D_SAE;
  const float4 z4 = {0.0f, 0.0f, 0.0f, 0.0f};
#pragma unroll
  for (int r = 0; r < 24; ++r)
    *reinterpret_cast<float4*>(zsrow + 4 * (r * 256 + t)) = z4;
  __syncthreads();
  if (t < KSEL) {
    if (sel_v[t]) zsrow[sel_i[t]] = __uint_as_float(sel_v[t]);   // skip padding
  }

  // ---- fused sparse decode ----
  float a0 = bd[t], a1 = bd[t + 256], a2 = bd[t + 512];
#pragma unroll 8
  for (int r = 0; r < KSEL; ++r) {
    const float v = __uint_as_float(sel_v[r]);
    const float* wr = Wd + (size_t)sel_i[r] * D_MODEL;
    a0 = fmaf(v, wr[t], a0);
    a1 = fmaf(v, wr[t + 256], a1);
    a2 = fmaf(v, wr[t + 512], a2);
  }
  float* xrow = Xr + (size_t)row * D_MODEL;
  xrow[t] = a0; xrow[t + 256] = a1; xrow[t + 512] = a2;
}

// ---------------------------------------------------------------------------
// ws-too-small fallback: R2's proven monolithic topk kernel
// ---------------------------------------------------------------------------
#define CAP 1792
__global__ __launch_bounds__(256, 4) void topk_scatter_decode(
    const float* __restrict__ Zpre, const float* __restrict__ Wd,
    const float* __restrict__ bd, float* __restrict__ Zs, float* __restrict__ Xr)
{
  __shared__ uint32_t cvA[CAP], ciA[CAP], cvB[CAP], ciB[CAP];
  __shared__ uint32_t hist[4][256];
  __shared__ uint32_t bitmap[D_SAE / 32];
  __shared__ uint32_t sel_v[KSEL], sel_i[KSEL];
  __shared__ int nc_sh, sel_sh, new_sh, bin_sh, cg_sh;

  const int row  = blockIdx.x;
  const int t    = threadIdx.x;
  const int wave = t >> 6;
  const float* zrow = Zpre + (size_t)row * D_SAE;

  if (t == 0) nc_sh = 0;
  __syncthreads();
  float T0 = 2.0f;
  int n_cur = 0;
  for (int tries = 0; ; ++tries) {
    for (int j4 = t; j4 < D_SAE / 4; j4 += 256) {
      const float4 z4 = *reinterpret_cast<const float4*>(zrow + 4 * j4);
      const float zz[4] = {z4.x, z4.y, z4.z, z4.w};
#pragma unroll
      for (int c = 0; c < 4; ++c) {
        const float v = zz[c] > 0.0f ? zz[c] : 0.0f;
        wave_append(cvA, ciA, &nc_sh, v > T0, __float_as_uint(v),
                    (uint32_t)(4 * j4 + c), CAP);
      }
    }
    __syncthreads();
    n_cur = nc_sh;
    if ((n_cur >= KSEL && n_cur <= CAP) || tries >= 9) break;
    __syncthreads();
    if (t == 0) nc_sh = 0;
    T0 = (n_cur < KSEL) ? ((tries >= 6) ? 0.0f : T0 * 0.25f) : T0 * 2.0f;
    __syncthreads();
  }
  if (n_cur > CAP) n_cur = CAP;

  if (t == 0) sel_sh = 0;
  __syncthreads();
  uint32_t* cv = cvA; uint32_t* ci = ciA;
  uint32_t* nv = cvB; uint32_t* ni = ciB;
  int need = KSEL;

  for (int L = 3; L >= 0; --L) {
    if (need <= 0 || n_cur <= 0) break;
    hist[0][t] = 0; hist[1][t] = 0; hist[2][t] = 0; hist[3][t] = 0;
    __syncthreads();
    for (int j = t; j < n_cur; j += 256)
      atomicAdd(&hist[wave][(cv[j] >> (L * 8)) & 255u], 1u);
    __syncthreads();
    if (t == 0) {
      int cum = 0, b = 255;
      for (; b >= 0; --b) {
        const int h = (int)(hist[0][b] + hist[1][b] + hist[2][b] + hist[3][b]);
        if (cum + h >= need) break;
        cum += h;
      }
      bin_sh = b; cg_sh = cum; new_sh = 0;
    }
    __syncthreads();
    const int B = bin_sh;
    const int rounds = (n_cur + 255) / 256;
    for (int rd = 0; rd < rounds; ++rd) {
      const int j = rd * 256 + t;
      const bool valid = j < n_cur;
      const uint32_t v  = valid ? cv[j] : 0u;
      const uint32_t ix = valid ? ci[j] : 0u;
      const int by = valid ? (int)((v >> (L * 8)) & 255u) : -1;
      wave_append(sel_v, sel_i, &sel_sh, valid && by > B, v, ix, KSEL);
      wave_append(nv, ni, &new_sh, valid && by == B, v, ix, CAP);
    }
    __syncthreads();
    need -= cg_sh;
    n_cur = new_sh < CAP ? new_sh : CAP;
    uint32_t* tv = cv; cv = nv; nv = tv;
    uint32_t* ti = ci; ci = ni; ni = ti;
  }

  if (t == 0) {
    int s = sel_sh;
    const int take = (need < n_cur ? need : n_cur);
    uint32_t last = 0u; bool first = true;
    for (int r = 0; r < take; ++r) {
      uint32_t best = 0xFFFFFFFFu, bv = 0u;
      for (int j = 0; j < n_cur; ++j) {
        const uint32_t ix = ci[j];
        if ((first || ix > last) && ix < best) { best = ix; bv = cv[j]; }
      }
      sel_v[s] = bv; sel_i[s] = best; ++s; last = best; first = false;
    }
    for (; s < KSEL; ++s) { sel_v[s] = 0u; sel_i[s] = 0u; }
  }
  __syncthreads();

  bitmap[t] = 0u; bitmap[t + 256] = 0u; bitmap[t + 512] = 0u;
  __syncthreads();
  if (t < KSEL && sel_v[t] != 0u)
    atomicOr(&bitmap[sel_i[t] >> 5], 1u << (sel_i[t] & 31));
  __syncthreads();

  float* zsrow = Zs + (size_t)row * D_SAE;
  for (int j4 = t; j4 < D_SAE / 4; j4 += 256) {
    const float4 z4 = *reinterpret_cast<const float4*>(zrow + 4 * j4);
    const float zz[4] = {z4.x, z4.y, z4.z, z4.w};
    const int base = 4 * j4;
    float oo[4];
#pragma unroll
    for (int c = 0; c < 4; ++c) {
      const int idx = base + c;
      const bool sel = (bitmap[idx >> 5] >> (idx & 31)) & 1u;
      const float v = zz[c] > 0.0f ? zz[c] : 0.0f;
      oo[c] = sel ? v : 0.0f;
    }
    float4 o; o.x = oo[0]; o.y = oo[1]; o.z = oo[2]; o.w = oo[3];
    *reinterpret_cast<float4*>(zsrow + base) = o;
  }

  float a0 = bd[t], a1 = bd[t + 256], a2 = bd[t + 512];
#pragma unroll 8
  for (int r = 0; r < KSEL; ++r) {
    const float v = __uint_as_float(sel_v[r]);
    const float* wr = Wd + (size_t)sel_i[r] * D_MODEL;
    a0 = fmaf(v, wr[t], a0);
    a1 = fmaf(v, wr[t + 256], a1);
    a2 = fmaf(v, wr[t + 512], a2);
  }
  float* xrow = Xr + (size_t)row * D_MODEL;
  xrow[t] = a0; xrow[t + 256] = a1; xrow[t + 512] = a2;
}

// ---------------------------------------------------------------------------
extern "C" void kernel_launch(void* const* d_in, const int* in_sizes, int n_in,
                              void* d_out, int out_size, void* d_ws, size_t ws_size,
                              hipStream_t stream) {
  const float* X  = (const float*)d_in[0];
  const float* We = (const float*)d_in[1];
  const float* be = (const float*)d_in[2];
  const float* Wd = (const float*)d_in[3];
  const float* bd = (const float*)d_in[4];

  float* out = (float*)d_out;
  float* Xr  = out;                                   // [4096, 768]
  float* Zs  = out + (size_t)NBATCH * D_MODEL;        // [4096, 24576]
  float* Zp  = Zs + (size_t)NBATCH * D_SAE;           // [4096, 24576]

  // f16 split scratch lives in the z_sparse region (overwritten later)
  _Float16* WhP = (_Float16*)Zs;
  _Float16* WlP = WhP + W_ELEMS;
  _Float16* XhP = WlP + W_ELEMS;
  _Float16* XlP = XhP + X_ELEMS;

  split_x<<<dim3(32 * 12), 256, 0, stream>>>(X, XhP, XlP);
  split_w<<<dim3(192 * 12), 256, 0, stream>>>(We, WhP, WlP);

  const size_t ws_needed = NBATCH * sizeof(int) +
                           (size_t)NBATCH * CAP_G * sizeof(uint2);
  if (ws_size >= ws_needed) {
    int*   cnt  = (int*)d_ws;
    uint2* cand = (uint2*)((char*)d_ws + NBATCH * sizeof(int));
    zero_cnt<<<dim3(16), 256, 0, stream>>>(cnt);
    gemm_split<1><<<dim3(32 * 192), 256, 0, stream>>>(XhP, XlP, WhP, WlP, be, Zp, cand, cnt);
    select_scatter_decode<<<dim3(NBATCH), 256, 0, stream>>>(Zp, cand, cnt, Wd, bd, Zs, Xr);
  } else {
    gemm_split<0><<<dim3(32 * 192), 256, 0, stream>>>(XhP, XlP, WhP, WlP, be, Zp, nullptr, nullptr);
    topk_scatter_decode<<<dim3(NBATCH), 256, 0, stream>>>(Zp, Wd, bd, Zs, Xr);
  }
}

// Round 5
// 1002.907 us; speedup vs baseline: 1.0467x; 1.0467x over previous
//
#include <hip/hip_runtime.h>
#include <cstdint>
#include <cstddef>

#define D_MODEL 768
#define D_SAE   24576
#define KSEL    32
#define NBATCH  4096

typedef _Float16 f16x8 __attribute__((ext_vector_type(8)));
typedef _Float16 f16x4 __attribute__((ext_vector_type(4)));
typedef float    f32x4 __attribute__((ext_vector_type(4)));

// f16 element counts of the split matrices (stored in the z_sparse region as scratch)
#define W_ELEMS  ((size_t)D_MODEL * D_SAE)   // 18,874,368
#define X_ELEMS  ((size_t)NBATCH * D_MODEL)  // 3,145,728

#define TCAND 2.0f      // candidate threshold: ~560 of 24576 N(0,1) exceed it
#define CAP_G 1536      // per-row global candidate capacity

// ---------------------------------------------------------------------------
// split_x: X[4096][768] f32 -> Xh,Xl' blocked f16  (xl' = (x - xh)*2^11)
// Tile = [128 m][64 k] f16 (16 KiB); within tile byte addr =
//   m*128 + ((k>>3)^(m&7))*16 + (k&7)*2   (XOR chunk swizzle baked in)
// ---------------------------------------------------------------------------
__global__ void split_x(const float* __restrict__ X,
                        _Float16* __restrict__ Xh, _Float16* __restrict__ Xl)
{
  const int tile = blockIdx.x;
  const int mb = tile / 12, kb = tile % 12;
  const int t = threadIdx.x;
#pragma unroll
  for (int r = 0; r < 8; ++r) {
    const int flat4 = r * 256 + t;          // 0..2047
    const int m  = flat4 >> 4;              // 0..127
    const int k4 = (flat4 & 15) << 2;       // 0,4,...,60
    const float4 v = *reinterpret_cast<const float4*>(
        &X[(size_t)(mb * 128 + m) * D_MODEL + kb * 64 + k4]);
    const float xx[4] = {v.x, v.y, v.z, v.w};
    f16x4 h, l;
#pragma unroll
    for (int c = 0; c < 4; ++c) {
      const _Float16 hh = (_Float16)xx[c];
      h[c] = hh;
      l[c] = (_Float16)((xx[c] - (float)hh) * 2048.0f);
    }
    const size_t base = ((size_t)(mb * 12 + kb)) * 8192 +
                        m * 64 + (((k4 >> 3) ^ (m & 7)) << 3) + (k4 & 7);
    *reinterpret_cast<f16x4*>(&Xh[base]) = h;
    *reinterpret_cast<f16x4*>(&Xl[base]) = l;
  }
}

// ---------------------------------------------------------------------------
// split_w: W[768][24576] f32 -> Wh,Wl' blocked-TRANSPOSED f16 tiles [n][k]
// ---------------------------------------------------------------------------
__global__ void split_w(const float* __restrict__ W,
                        _Float16* __restrict__ Wh, _Float16* __restrict__ Wl)
{
  __shared__ float Ws[64][129];
  const int tile = blockIdx.x;
  const int nb = tile / 12, kb = tile % 12;
  const int t = threadIdx.x;
#pragma unroll
  for (int r = 0; r < 8; ++r) {
    const int flat4 = r * 256 + t;
    const int k  = flat4 >> 5;              // 0..63
    const int n4 = (flat4 & 31) << 2;       // 0..124
    const float4 v = *reinterpret_cast<const float4*>(
        &W[(size_t)(kb * 64 + k) * D_SAE + nb * 128 + n4]);
    Ws[k][n4 + 0] = v.x; Ws[k][n4 + 1] = v.y; Ws[k][n4 + 2] = v.z; Ws[k][n4 + 3] = v.w;
  }
  __syncthreads();
#pragma unroll
  for (int r = 0; r < 4; ++r) {
    const int u = r * 256 + t;              // 0..1023
    const int n = u >> 3;                   // 0..127
    const int c = u & 7;                    // k-octet
    f16x8 h, l;
#pragma unroll
    for (int i = 0; i < 8; ++i) {
      const float w = Ws[c * 8 + i][n];
      const _Float16 hh = (_Float16)w;
      h[i] = hh;
      l[i] = (_Float16)((w - (float)hh) * 2048.0f);
    }
    const size_t base = ((size_t)(nb * 12 + kb)) * 8192 + n * 64 + ((c ^ (n & 7)) << 3);
    *reinterpret_cast<f16x8*>(&Wh[base]) = h;
    *reinterpret_cast<f16x8*>(&Wl[base]) = l;
  }
}

// ---------------------------------------------------------------------------
__global__ void zero_cnt(int* cnt) { cnt[blockIdx.x * 256 + threadIdx.x] = 0; }

// ---------------------------------------------------------------------------
// gemm_split: 3-pass, one accumulator set, BM=256 x BN=128, BK=64, 512 thr.
// Zp = ((Xh@Wl' + Xl'@Wh)*2^-11 + Xh@Wh) + be.
// 8 waves as 4m x 2n; wave owns 64x64 (4x4 16x16x32 frags). LDS 48KB -> 3/CU.
// ---------------------------------------------------------------------------
__device__ __forceinline__ void gll16(void* lds, const void* g) {
  __builtin_amdgcn_global_load_lds(
      (const __attribute__((address_space(1))) unsigned int*)g,
      (__attribute__((address_space(3))) unsigned int*)lds, 16, 0, 0);
}

template <int APPEND>
__global__ __launch_bounds__(512, 4) void gemm_split(
    const _Float16* __restrict__ Xh, const _Float16* __restrict__ Xl,
    const _Float16* __restrict__ Wh, const _Float16* __restrict__ Wl,
    const float* __restrict__ be, float* __restrict__ Zp,
    uint2* __restrict__ cand, int* __restrict__ cnt)
{
  __shared__ char lds[49152];
  char* As = lds;             // two 16 KB m-tiles (rows 0-127, 128-255)
  char* Bs = lds + 32768;     // one 16 KB n-tile

  const int bid = blockIdx.x;
  const int wg  = (bid & 7) * 384 + (bid >> 3);   // XCD-contiguous (3072%8==0)
  const int mb  = wg & 15;                        // m fastest within XCD chunk
  const int nb  = wg >> 4;

  const int t = threadIdx.x, lane = t & 63, w = t >> 6;
  const int wm = w >> 1, wn = w & 1;              // 4m x 2n wave grid
  const int l15 = lane & 15, lq = lane >> 4;
  const int c0 = lq ^ (lane & 7);
  // A frag: tile (wm>>1), row (wm&1)*64 + i*16 + l15  (row&7 == lane&7)
  const int offA0 = (wm >> 1) * 16384 + ((wm & 1) * 64 + l15) * 128 + c0 * 16;
  const int offB0 = (wn * 64 + l15) * 128 + c0 * 16;

  f32x4 acc[4][4] = {};

  const char* tAh = (const char*)Xh + (size_t)(mb * 2 * 12) * 16384;
  const char* tAl = (const char*)Xl + (size_t)(mb * 2 * 12) * 16384;
  const char* tBh = (const char*)Wh + (size_t)(nb * 12) * 16384;
  const char* tBl = (const char*)Wl + (size_t)(nb * 12) * 16384;

  const int dstoff = (t & 448) * 16;   // wave-uniform LDS base (+ lane*16 implicit)

  auto run_pass = [&](const char* Ag, const char* Bg) {
    for (int ks = 0; ks < 12; ++ks) {
      __syncthreads();                           // prior readers done
      const char* a0 = Ag + ks * 16384 + t * 16;            // m-tile 2mb
      const char* a1 = Ag + 196608 + ks * 16384 + t * 16;   // m-tile 2mb+1
      const char* b0 = Bg + ks * 16384 + t * 16;
#pragma unroll
      for (int r = 0; r < 2; ++r) {              // 512 thr x 16B = 8 KB/round
        gll16(As + dstoff + r * 8192,          a0 + r * 8192);
        gll16(As + 16384 + dstoff + r * 8192,  a1 + r * 8192);
        gll16(Bs + dstoff + r * 8192,          b0 + r * 8192);
      }
      asm volatile("s_waitcnt vmcnt(0)" ::: "memory");
      __syncthreads();
#pragma unroll
      for (int kk = 0; kk < 2; ++kk) {
        f16x8 a[4], b[4];
#pragma unroll
        for (int i = 0; i < 4; ++i)
          a[i] = *reinterpret_cast<const f16x8*>(As + ((offA0 + i * 2048) ^ (kk * 64)));
#pragma unroll
        for (int j = 0; j < 4; ++j)
          b[j] = *reinterpret_cast<const f16x8*>(Bs + ((offB0 + j * 2048) ^ (kk * 64)));
#pragma unroll
        for (int i = 0; i < 4; ++i)
#pragma unroll
          for (int j = 0; j < 4; ++j)
            acc[i][j] = __builtin_amdgcn_mfma_f32_16x16x32_f16(a[i], b[j], acc[i][j], 0, 0, 0);
      }
    }
  };

  run_pass(tAh, tBl);                 // xh @ Wl'
  run_pass(tAl, tBh);                 // xl' @ Wh
#pragma unroll
  for (int i = 0; i < 4; ++i)
#pragma unroll
    for (int j = 0; j < 4; ++j) acc[i][j] *= (1.0f / 2048.0f);
  run_pass(tAh, tBh);                 // + xh @ Wh

  // epilogue: + b_enc, store, optional candidate append
  // C/D layout: col = lane&15, row = lq*4 + reg
  const int m0  = mb * 256 + wm * 64 + (lq << 2);
  const int n0g = nb * 128 + wn * 64 + l15;
#pragma unroll
  for (int j = 0; j < 4; ++j) {
    const int col = n0g + j * 16;
    const float bej = be[col];
#pragma unroll
    for (int i = 0; i < 4; ++i) {
      float* dst = &Zp[(size_t)(m0 + i * 16) * D_SAE + col];
#pragma unroll
      for (int rg = 0; rg < 4; ++rg) {
        const float o = acc[i][j][rg] + bej;
        dst[(size_t)rg * D_SAE] = o;
        if (APPEND && o > TCAND) {
          const int row = m0 + i * 16 + rg;
          const int slot = atomicAdd(&cnt[row], 1);
          if (slot < CAP_G)
            cand[(size_t)row * CAP_G + slot] = make_uint2(__float_as_uint(o), (uint32_t)col);
        }
      }
    }
  }
}

// ---------------------------------------------------------------------------
// wave ballot-compacted LDS append
// ---------------------------------------------------------------------------
__device__ __forceinline__ void wave_append(uint32_t* dv, uint32_t* di, int* counter,
                                            bool pred, uint32_t v, uint32_t idx, int cap)
{
  const unsigned long long m = __ballot(pred ? 1 : 0);
  if (m == 0ull) return;
  const int lane = threadIdx.x & 63;
  const int leader = __ffsll(m) - 1;
  int wbase = 0;
  if (lane == leader) wbase = atomicAdd(counter, __popcll(m));
  wbase = __shfl(wbase, leader);
  if (pred) {
    const int p = wbase + (int)__popcll(m & ((1ull << lane) - 1ull));
    if (p < cap) { dv[p] = v; di[p] = idx; }
  }
}

// ---------------------------------------------------------------------------
// select_scatter_decode: per row, exact top-32 from the candidate list
// (fallback: full Zpre rescan if count outside [KSEL, CAP_G]), then zero-fill
// z_sparse row + scatter 32 + fused sparse decode.
// ---------------------------------------------------------------------------
__global__ __launch_bounds__(256, 4) void select_scatter_decode(
    const float* __restrict__ Zpre, const uint2* __restrict__ cand,
    const int* __restrict__ cnt, const float* __restrict__ Wd,
    const float* __restrict__ bd, float* __restrict__ Zs, float* __restrict__ Xr)
{
  __shared__ uint32_t cvA[CAP_G], ciA[CAP_G], cvB[CAP_G], ciB[CAP_G];
  __shared__ uint32_t hist[4][256];
  __shared__ uint32_t sel_v[KSEL], sel_i[KSEL];
  __shared__ int nc_sh, sel_sh, new_sh, bin_sh, cg_sh;

  const int row  = blockIdx.x;
  const int t    = threadIdx.x;
  const int wave = t >> 6;
  const int n_glob = cnt[row];
  int n_cur;

  if (n_glob >= KSEL && n_glob <= CAP_G) {
    for (int j = t; j < n_glob; j += 256) {
      const uint2 p = cand[(size_t)row * CAP_G + j];
      cvA[j] = p.x; ciA[j] = p.y;
    }
    n_cur = n_glob;
    __syncthreads();
  } else {
    // rare fallback: adaptive-threshold full-row scan
    const float* zrow = Zpre + (size_t)row * D_SAE;
    if (t == 0) nc_sh = 0;
    __syncthreads();
    float T0 = (n_glob > CAP_G) ? 4.0f : 0.5f;
    for (int tries = 0; ; ++tries) {
      for (int j4 = t; j4 < D_SAE / 4; j4 += 256) {
        const float4 z4 = *reinterpret_cast<const float4*>(zrow + 4 * j4);
        const float zz[4] = {z4.x, z4.y, z4.z, z4.w};
#pragma unroll
        for (int c = 0; c < 4; ++c) {
          const float v = zz[c] > 0.0f ? zz[c] : 0.0f;
          wave_append(cvA, ciA, &nc_sh, v > T0, __float_as_uint(v),
                      (uint32_t)(4 * j4 + c), CAP_G);
        }
      }
      __syncthreads();
      n_cur = nc_sh;
      if ((n_cur >= KSEL && n_cur <= CAP_G) || tries >= 9) break;
      __syncthreads();
      if (t == 0) nc_sh = 0;
      T0 = (n_cur < KSEL) ? ((tries >= 6) ? 0.0f : T0 * 0.25f) : T0 * 2.0f;
      __syncthreads();
    }
    if (n_cur > CAP_G) n_cur = CAP_G;
  }

  // ---- radix select top-32 (all values >= 0 => bit pattern monotone) ----
  if (t == 0) sel_sh = 0;
  __syncthreads();
  uint32_t* cv = cvA; uint32_t* ci = ciA;
  uint32_t* nv = cvB; uint32_t* ni = ciB;
  int need = KSEL;

  for (int L = 3; L >= 0; --L) {
    if (need <= 0 || n_cur <= 0) break;
    hist[0][t] = 0; hist[1][t] = 0; hist[2][t] = 0; hist[3][t] = 0;
    __syncthreads();
    for (int j = t; j < n_cur; j += 256)
      atomicAdd(&hist[wave][(cv[j] >> (L * 8)) & 255u], 1u);
    __syncthreads();
    if (t == 0) {
      int cum = 0, b = 255;
      for (; b >= 0; --b) {
        const int h = (int)(hist[0][b] + hist[1][b] + hist[2][b] + hist[3][b]);
        if (cum + h >= need) break;
        cum += h;
      }
      bin_sh = b; cg_sh = cum; new_sh = 0;
    }
    __syncthreads();
    const int B = bin_sh;
    const int rounds = (n_cur + 255) / 256;
    for (int rd = 0; rd < rounds; ++rd) {
      const int j = rd * 256 + t;
      const bool valid = j < n_cur;
      const uint32_t v  = valid ? cv[j] : 0u;
      const uint32_t ix = valid ? ci[j] : 0u;
      const int by = valid ? (int)((v >> (L * 8)) & 255u) : -1;
      wave_append(sel_v, sel_i, &sel_sh, valid && by > B, v, ix, KSEL);
      wave_append(nv, ni, &new_sh, valid && by == B, v, ix, CAP_G);
    }
    __syncthreads();
    need -= cg_sh;
    n_cur = new_sh < CAP_G ? new_sh : CAP_G;
    uint32_t* tv = cv; cv = nv; nv = tv;
    uint32_t* ti = ci; ci = ni; ni = ti;
  }

  // ---- exact-tie fill (lowest indices first) + val==0 padding ----
  if (t == 0) {
    int s = sel_sh;
    const int take = (need < n_cur ? need : n_cur);
    uint32_t last = 0u; bool first = true;
    for (int r = 0; r < take; ++r) {
      uint32_t best = 0xFFFFFFFFu, bv = 0u;
      for (int j = 0; j < n_cur; ++j) {
        const uint32_t ix = ci[j];
        if ((first || ix > last) && ix < best) { best = ix; bv = cv[j]; }
      }
      sel_v[s] = bv; sel_i[s] = best; ++s; last = best; first = false;
    }
    for (; s < KSEL; ++s) { sel_v[s] = 0u; sel_i[s] = 0u; }
  }
  __syncthreads();

  // ---- zero-fill z_sparse row + scatter 32 ----
  float* zsrow = Zs + (size_t)row * D_SAE;
  const float4 z4 = {0.0f, 0.0f, 0.0f, 0.0f};
#pragma unroll
  for (int r = 0; r < 24; ++r)
    *reinterpret_cast<float4*>(zsrow + 4 * (r * 256 + t)) = z4;
  __syncthreads();
  if (t < KSEL) {
    if (sel_v[t]) zsrow[sel_i[t]] = __uint_as_float(sel_v[t]);   // skip padding
  }

  // ---- fused sparse decode ----
  float a0 = bd[t], a1 = bd[t + 256], a2 = bd[t + 512];
#pragma unroll 8
  for (int r = 0; r < KSEL; ++r) {
    const float v = __uint_as_float(sel_v[r]);
    const float* wr = Wd + (size_t)sel_i[r] * D_MODEL;
    a0 = fmaf(v, wr[t], a0);
    a1 = fmaf(v, wr[t + 256], a1);
    a2 = fmaf(v, wr[t + 512], a2);
  }
  float* xrow = Xr + (size_t)row * D_MODEL;
  xrow[t] = a0; xrow[t + 256] = a1; xrow[t + 512] = a2;
}

// ---------------------------------------------------------------------------
// ws-too-small fallback: R2's proven monolithic topk kernel
// ---------------------------------------------------------------------------
#define CAP 1792
__global__ __launch_bounds__(256, 4) void topk_scatter_decode(
    const float* __restrict__ Zpre, const float* __restrict__ Wd,
    const float* __restrict__ bd, float* __restrict__ Zs, float* __restrict__ Xr)
{
  __shared__ uint32_t cvA[CAP], ciA[CAP], cvB[CAP], ciB[CAP];
  __shared__ uint32_t hist[4][256];
  __shared__ uint32_t bitmap[D_SAE / 32];
  __shared__ uint32_t sel_v[KSEL], sel_i[KSEL];
  __shared__ int nc_sh, sel_sh, new_sh, bin_sh, cg_sh;

  const int row  = blockIdx.x;
  const int t    = threadIdx.x;
  const int wave = t >> 6;
  const float* zrow = Zpre + (size_t)row * D_SAE;

  if (t == 0) nc_sh = 0;
  __syncthreads();
  float T0 = 2.0f;
  int n_cur = 0;
  for (int tries = 0; ; ++tries) {
    for (int j4 = t; j4 < D_SAE / 4; j4 += 256) {
      const float4 z4 = *reinterpret_cast<const float4*>(zrow + 4 * j4);
      const float zz[4] = {z4.x, z4.y, z4.z, z4.w};
#pragma unroll
      for (int c = 0; c < 4; ++c) {
        const float v = zz[c] > 0.0f ? zz[c] : 0.0f;
        wave_append(cvA, ciA, &nc_sh, v > T0, __float_as_uint(v),
                    (uint32_t)(4 * j4 + c), CAP);
      }
    }
    __syncthreads();
    n_cur = nc_sh;
    if ((n_cur >= KSEL && n_cur <= CAP) || tries >= 9) break;
    __syncthreads();
    if (t == 0) nc_sh = 0;
    T0 = (n_cur < KSEL) ? ((tries >= 6) ? 0.0f : T0 * 0.25f) : T0 * 2.0f;
    __syncthreads();
  }
  if (n_cur > CAP) n_cur = CAP;

  if (t == 0) sel_sh = 0;
  __syncthreads();
  uint32_t* cv = cvA; uint32_t* ci = ciA;
  uint32_t* nv = cvB; uint32_t* ni = ciB;
  int need = KSEL;

  for (int L = 3; L >= 0; --L) {
    if (need <= 0 || n_cur <= 0) break;
    hist[0][t] = 0; hist[1][t] = 0; hist[2][t] = 0; hist[3][t] = 0;
    __syncthreads();
    for (int j = t; j < n_cur; j += 256)
      atomicAdd(&hist[wave][(cv[j] >> (L * 8)) & 255u], 1u);
    __syncthreads();
    if (t == 0) {
      int cum = 0, b = 255;
      for (; b >= 0; --b) {
        const int h = (int)(hist[0][b] + hist[1][b] + hist[2][b] + hist[3][b]);
        if (cum + h >= need) break;
        cum += h;
      }
      bin_sh = b; cg_sh = cum; new_sh = 0;
    }
    __syncthreads();
    const int B = bin_sh;
    const int rounds = (n_cur + 255) / 256;
    for (int rd = 0; rd < rounds; ++rd) {
      const int j = rd * 256 + t;
      const bool valid = j < n_cur;
      const uint32_t v  = valid ? cv[j] : 0u;
      const uint32_t ix = valid ? ci[j] : 0u;
      const int by = valid ? (int)((v >> (L * 8)) & 255u) : -1;
      wave_append(sel_v, sel_i, &sel_sh, valid && by > B, v, ix, KSEL);
      wave_append(nv, ni, &new_sh, valid && by == B, v, ix, CAP);
    }
    __syncthreads();
    need -= cg_sh;
    n_cur = new_sh < CAP ? new_sh : CAP;
    uint32_t* tv = cv; cv = nv; nv = tv;
    uint32_t* ti = ci; ci = ni; ni = ti;
  }

  if (t == 0) {
    int s = sel_sh;
    const int take = (need < n_cur ? need : n_cur);
    uint32_t last = 0u; bool first = true;
    for (int r = 0; r < take; ++r) {
      uint32_t best = 0xFFFFFFFFu, bv = 0u;
      for (int j = 0; j < n_cur; ++j) {
        const uint32_t ix = ci[j];
        if ((first || ix > last) && ix < best) { best = ix; bv = cv[j]; }
      }
      sel_v[s] = bv; sel_i[s] = best; ++s; last = best; first = false;
    }
    for (; s < KSEL; ++s) { sel_v[s] = 0u; sel_i[s] = 0u; }
  }
  __syncthreads();

  bitmap[t] = 0u; bitmap[t + 256] = 0u; bitmap[t + 512] = 0u;
  __syncthreads();
  if (t < KSEL && sel_v[t] != 0u)
    atomicOr(&bitmap[sel_i[t] >> 5], 1u << (sel_i[t] & 31));
  __syncthreads();

  float* zsrow = Zs + (size_t)row * D_SAE;
  for (int j4 = t; j4 < D_SAE / 4; j4 += 256) {
    const float4 z4 = *reinterpret_cast<const float4*>(zrow + 4 * j4);
    const float zz[4] = {z4.x, z4.y, z4.z, z4.w};
    const int base = 4 * j4;
    float oo[4];
#pragma unroll
    for (int c = 0; c < 4; ++c) {
      const int idx = base + c;
      const bool sel = (bitmap[idx >> 5] >> (idx & 31)) & 1u;
      const float v = zz[c] > 0.0f ? zz[c] : 0.0f;
      oo[c] = sel ? v : 0.0f;
    }
    float4 o; o.x = oo[0]; o.y = oo[1]; o.z = oo[2]; o.w = oo[3];
    *reinterpret_cast<float4*>(zsrow + base) = o;
  }

  float a0 = bd[t], a1 = bd[t + 256], a2 = bd[t + 512];
#pragma unroll 8
  for (int r = 0; r < KSEL; ++r) {
    const float v = __uint_as_float(sel_v[r]);
    const float* wr = Wd + (size_t)sel_i[r] * D_MODEL;
    a0 = fmaf(v, wr[t], a0);
    a1 = fmaf(v, wr[t + 256], a1);
    a2 = fmaf(v, wr[t + 512], a2);
  }
  float* xrow = Xr + (size_t)row * D_MODEL;
  xrow[t] = a0; xrow[t + 256] = a1; xrow[t + 512] = a2;
}

// ---------------------------------------------------------------------------
extern "C" void kernel_launch(void* const* d_in, const int* in_sizes, int n_in,
                              void* d_out, int out_size, void* d_ws, size_t ws_size,
                              hipStream_t stream) {
  const float* X  = (const float*)d_in[0];
  const float* We = (const float*)d_in[1];
  const float* be = (const float*)d_in[2];
  const float* Wd = (const float*)d_in[3];
  const float* bd = (const float*)d_in[4];

  float* out = (float*)d_out;
  float* Xr  = out;                                   // [4096, 768]
  float* Zs  = out + (size_t)NBATCH * D_MODEL;        // [4096, 24576]
  float* Zp  = Zs + (size_t)NBATCH * D_SAE;           // [4096, 24576]

  // f16 split scratch lives in the z_sparse region (overwritten later)
  _Float16* WhP = (_Float16*)Zs;
  _Float16* WlP = WhP + W_ELEMS;
  _Float16* XhP = WlP + W_ELEMS;
  _Float16* XlP = XhP + X_ELEMS;

  split_x<<<dim3(32 * 12), 256, 0, stream>>>(X, XhP, XlP);
  split_w<<<dim3(192 * 12), 256, 0, stream>>>(We, WhP, WlP);

  const size_t ws_needed = NBATCH * sizeof(int) +
                           (size_t)NBATCH * CAP_G * sizeof(uint2);
  if (ws_size >= ws_needed) {
    int*   cnt  = (int*)d_ws;
    uint2* cand = (uint2*)((char*)d_ws + NBATCH * sizeof(int));
    zero_cnt<<<dim3(16), 256, 0, stream>>>(cnt);
    gemm_split<1><<<dim3(16 * 192), 512, 0, stream>>>(XhP, XlP, WhP, WlP, be, Zp, cand, cnt);
    select_scatter_decode<<<dim3(NBATCH), 256, 0, stream>>>(Zp, cand, cnt, Wd, bd, Zs, Xr);
  } else {
    gemm_split<0><<<dim3(16 * 192), 512, 0, stream>>>(XhP, XlP, WhP, WlP, be, Zp, nullptr, nullptr);
    topk_scatter_decode<<<dim3(NBATCH), 256, 0, stream>>>(Zp, Wd, bd, Zs, Xr);
  }
}